// Round 2
// baseline (2998.474 us; speedup 1.0000x reference)
//
#include <hip/hip_runtime.h>
#include <hip/hip_bf16.h>

// Problem constants fixed by setup_inputs()
#define NNODE   20000
#define BS      8
#define NEG1    33
#define DDIM    32
#define NLAYER  6
#define NRELX2  128     // 2*N_REL
#define FEAT    256     // BS*DDIM
#define INW     416     // 13*DDIM
#define NPB     16      // nodes per block
#define NPG     8       // nodes per inner group (accs in flight)

// ---------------------------------------------------------------- precompute
__global__ void count_kernel(const int* __restrict__ es, const int* __restrict__ ed,
                             int* __restrict__ cnt, int E) {
    int i = blockIdx.x * 256 + threadIdx.x;
    if (i >= 2 * E) return;
    int dst = (i < E) ? ed[i] : es[i - E];
    atomicAdd(&cnt[dst], 1);
}

__global__ void scan_kernel(const int* __restrict__ cnt, int* __restrict__ row_ptr, int N) {
    __shared__ int sh[1024];
    __shared__ int s_carry;
    if (threadIdx.x == 0) { s_carry = 0; row_ptr[0] = 0; }
    __syncthreads();
    for (int base = 0; base < N; base += 1024) {
        int i = base + threadIdx.x;
        int v = (i < N) ? cnt[i] : 0;
        sh[threadIdx.x] = v;
        __syncthreads();
        for (int off = 1; off < 1024; off <<= 1) {
            int t = (threadIdx.x >= off) ? sh[threadIdx.x - off] : 0;
            __syncthreads();
            sh[threadIdx.x] += t;
            __syncthreads();
        }
        int carry = s_carry;
        if (i < N) row_ptr[i + 1] = carry + sh[threadIdx.x];
        __syncthreads();
        if (threadIdx.x == 1023) s_carry = carry + sh[1023];
        __syncthreads();
    }
}

__global__ void fill_kernel(const int* __restrict__ es, const int* __restrict__ ed,
                            const int* __restrict__ et, const int* __restrict__ row_ptr,
                            int* __restrict__ cursor, int* __restrict__ csr_src,
                            int* __restrict__ csr_et, int E) {
    int i = blockIdx.x * 256 + threadIdx.x;
    if (i >= 2 * E) return;
    int src, dst, ty;
    if (i < E) { src = es[i]; dst = ed[i]; ty = et[i]; }
    else       { src = ed[i - E]; dst = es[i - E]; ty = et[i - E] + 64; }
    int pos = row_ptr[dst] + atomicAdd(&cursor[dst], 1);
    csr_src[pos] = src;
    csr_et[pos]  = ty;
}

__global__ void deg_kernel(const int* __restrict__ cnt, float* __restrict__ dinv,
                           float* __restrict__ logdeg, int N) {
    int n = blockIdx.x * 256 + threadIdx.x;
    if (n >= N) return;
    float deg = (float)cnt[n] + 1.0f;
    dinv[n] = 1.0f / deg;
    logdeg[n] = logf(deg);
}

__global__ void mean_kernel(const float* __restrict__ logdeg, float* __restrict__ meanout, int N) {
    __shared__ float sh[256];
    float s = 0.f;
    for (int i = threadIdx.x; i < N; i += 256) s += logdeg[i];
    sh[threadIdx.x] = s;
    __syncthreads();
    for (int off = 128; off > 0; off >>= 1) {
        if (threadIdx.x < off) sh[threadIdx.x] += sh[threadIdx.x + off];
        __syncthreads();
    }
    if (threadIdx.x == 0) meanout[0] = sh[0] / (float)N;
}

__global__ void sc_kernel(const float* __restrict__ logdeg, const float* __restrict__ meanp,
                          float* __restrict__ sc, int N) {
    int n = blockIdx.x * 256 + threadIdx.x;
    if (n >= N) return;
    sc[n] = logdeg[n] / meanp[0];
}

__global__ void prep_kernel(const int* __restrict__ h_index, const int* __restrict__ t_index,
                            const int* __restrict__ r_index, const float* __restrict__ rel_query,
                            int* __restrict__ h0, int* __restrict__ r0,
                            float* __restrict__ query, int* __restrict__ tnew) {
    __shared__ int s_isneg[BS];
    __shared__ int s_r0[BS];
    int t = threadIdx.x;
    if (t < BS) {
        int b = t;
        int hv = h_index[b * NEG1];
        int all = 1;
        for (int j = 1; j < NEG1; j++) all &= (h_index[b * NEG1 + j] == hv);
        s_isneg[b] = all;
        int h0v = all ? hv : t_index[b * NEG1];
        int r0v = all ? r_index[b * NEG1] : r_index[b * NEG1] + 64;
        s_r0[b] = r0v;
        h0[b] = h0v;
        r0[b] = r0v;
    }
    __syncthreads();
    {
        int b = t >> 5, dd = t & 31;
        query[t] = rel_query[s_r0[b] * DDIM + dd];
    }
    for (int idx = t; idx < BS * NEG1; idx += 256) {
        int b = idx / NEG1;
        tnew[idx] = s_isneg[b] ? t_index[idx] : h_index[idx];
    }
}

__global__ void rel_kernel(const float* __restrict__ rel_query, const float* __restrict__ Wrel,
                           const float* __restrict__ brel, float* __restrict__ rel_all) {
    int idx = blockIdx.x * 256 + threadIdx.x;
    if (idx >= NLAYER * NRELX2 * DDIM) return;
    int i  = idx >> 12;          // / 4096
    int q  = (idx >> 5) & 127;
    int dd = idx & 31;
    float acc = brel[i * DDIM + dd];
    #pragma unroll
    for (int k = 0; k < DDIM; k++)
        acc = fmaf(rel_query[q * DDIM + k], Wrel[i * DDIM * DDIM + k * DDIM + dd], acc);
    rel_all[idx] = acc;
}

// Wg[i][j][c][dd] = Wlin[i][k_j(dd)][(dd+c)&31]  — systolic-shuffled weights
__global__ void wg_kernel(const float* __restrict__ Wlin, float* __restrict__ wg) {
    int idx = blockIdx.x * 256 + threadIdx.x;       // NLAYER*13*32*32
    if (idx >= NLAYER * 13 * 32 * 32) return;
    int dd = idx & 31;
    int c  = (idx >> 5) & 31;
    int rest = idx >> 10;       // i*13 + j
    int j = rest % 13;
    int i = rest / 13;
    int k;
    if (j == 0) k = dd;
    else { int s = (j - 1) / 3, scl = (j - 1) % 3; k = 32 + (dd * 4 + s) * 3 + scl; }
    int col = (dd + c) & 31;
    wg[idx] = Wlin[(i * INW + k) * DDIM + col];
}

__global__ void init_x_kernel(float* __restrict__ x, const int* __restrict__ h0,
                              const float* __restrict__ query) {
    int i = blockIdx.x * 256 + threadIdx.x;
    if (i >= NNODE * FEAT) return;
    int n = i >> 8;
    int t = i & 255;
    int b = t >> 5;
    x[i] = (h0[b] == n) ? query[t] : 0.f;
}

// ---------------------------------------------------------------- main layer
// Per block: NPB nodes. Threads (b,dd). Stats in registers; GEMM via systolic
// accumulator rotation (1 ds_bpermute/step) with pre-shuffled coalesced W.
__global__ __launch_bounds__(256, 5) void layer_kernel(
    const float* __restrict__ x_in, float* __restrict__ x_out,
    const int* __restrict__ row_ptr, const int* __restrict__ csr_src,
    const int* __restrict__ csr_et,
    const float* __restrict__ rel_i,     // [128][32]
    const float* __restrict__ wg_i,      // [13][32][32]
    const float* __restrict__ blin_i, const float* __restrict__ g_i,
    const float* __restrict__ b_i,
    const float* __restrict__ dinv, const float* __restrict__ sc,
    const int* __restrict__ h0, const float* __restrict__ query) {
    int t  = threadIdx.x;
    int b  = t >> 5, dd = t & 31;
    int lane = t & 63;
    __shared__ float s_rel[NRELX2 * DDIM];   // 16 KB

    for (int k = t; k < NRELX2 * DDIM; k += 256) s_rel[k] = rel_i[k];

    float q   = query[t];
    int   h0b = h0[b];
    float gdd = g_i[dd], bdd = b_i[dd], bl = blin_i[dd];
    // rotate-down-by-1 within each 32-lane half of the wave (pull from lane+1)
    int bperm_addr = ((((lane + 1) & 31) | (lane & 32)) << 2);
    __syncthreads();

    int nbase = blockIdx.x * NPB;
    for (int g = 0; g < NPB; g += NPG) {
        // -------- edge / stats phase (registers only)
        float xm[NPG], mean[NPG], mx[NPG], mn[NPG], stdv[NPG], scv[NPG], sc2[NPG];
        #pragma unroll
        for (int u = 0; u < NPG; ++u) {
            int n = nbase + g + u;
            float bval = (h0b == n) ? q : 0.f;     // boundary self-entry
            float sum = bval, ssq = bval * bval, vmx = bval, vmn = bval;
            int e0 = row_ptr[n], e1 = row_ptr[n + 1];
            for (int e = e0; e < e1; ++e) {
                int s  = csr_src[e];
                int ty = csr_et[e];
                float m = x_in[s * FEAT + t] * s_rel[ty * DDIM + dd];
                sum += m; ssq += m * m;
                vmx = fmaxf(vmx, m); vmn = fminf(vmn, m);
            }
            float dv = dinv[n];
            float me = sum * dv, sq = ssq * dv;
            mean[u] = me; mx[u] = vmx; mn[u] = vmn;
            stdv[u] = sqrtf(fmaxf(sq - me * me, 1e-6f));
            float sv = sc[n];
            scv[u] = sv; sc2[u] = 1.0f / fmaxf(sv, 0.01f);
            xm[u]  = x_in[n * FEAT + t];
        }

        // -------- systolic GEMM: acc for output col o visits lane (o-i)&31 at step i
        float acc[NPG];
        #pragma unroll
        for (int u = 0; u < NPG; ++u) acc[u] = bl;   // lane dd starts holding col dd
        #pragma unroll
        for (int i = 0; i < 32; ++i) {
            float w[13];
            #pragma unroll
            for (int j = 0; j < 13; ++j)
                w[j] = wg_i[(j * 32 + i) * 32 + dd];   // coalesced: Wg[j][i][dd]
            #pragma unroll
            for (int u = 0; u < NPG; ++u) {
                float a = acc[u];
                a = fmaf(xm[u], w[0], a);
                float t0 = fmaf(scv[u], w[2],  w[1]);  t0 = fmaf(sc2[u], w[3],  t0);
                a = fmaf(mean[u], t0, a);
                float t1 = fmaf(scv[u], w[5],  w[4]);  t1 = fmaf(sc2[u], w[6],  t1);
                a = fmaf(mx[u],   t1, a);
                float t2 = fmaf(scv[u], w[8],  w[7]);  t2 = fmaf(sc2[u], w[9],  t2);
                a = fmaf(mn[u],   t2, a);
                float t3 = fmaf(scv[u], w[11], w[10]); t3 = fmaf(sc2[u], w[12], t3);
                a = fmaf(stdv[u], t3, a);
                acc[u] = a;
            }
            #pragma unroll
            for (int u = 0; u < NPG; ++u)
                acc[u] = __int_as_float(__builtin_amdgcn_ds_bpermute(
                             bperm_addr, __float_as_int(acc[u])));
        }
        // 32 rotations = identity: lane dd again holds col dd

        // -------- LayerNorm + ReLU + residual + store
        #pragma unroll
        for (int u = 0; u < NPG; ++u) {
            int n = nbase + g + u;
            float v = acc[u];
            float s1 = v;
            #pragma unroll
            for (int m2 = 16; m2 >= 1; m2 >>= 1) s1 += __shfl_xor(s1, m2, 32);
            float lmean = s1 * (1.0f / 32.0f);
            float dlt = v - lmean;
            float s2 = dlt * dlt;
            #pragma unroll
            for (int m2 = 16; m2 >= 1; m2 >>= 1) s2 += __shfl_xor(s2, m2, 32);
            float var = s2 * (1.0f / 32.0f);
            float y = dlt / sqrtf(var + 1e-5f) * gdd + bdd;
            y = fmaxf(y, 0.0f);
            x_out[n * FEAT + t] = y + xm[u];
        }
    }
}

// ---------------------------------------------------------------- readout
__global__ void score_kernel(const float* __restrict__ x, const int* __restrict__ tnew,
                             const float* __restrict__ query,
                             const float* __restrict__ W1, const float* __restrict__ b1,
                             const float* __restrict__ W2, const float* __restrict__ b2,
                             float* __restrict__ out) {
    int idx = blockIdx.x;         // b*33+j
    int b = idx / NEG1;
    int k = threadIdx.x;          // 0..63
    __shared__ float v[64];
    int tnode = tnew[idx];
    if (k < 32) v[k] = x[tnode * FEAT + b * DDIM + k];
    else        v[k] = query[b * DDIM + (k - 32)];
    __syncthreads();
    float acc = b1[k];
    #pragma unroll
    for (int l = 0; l < 64; l++) acc = fmaf(v[l], W1[l * 64 + k], acc);
    acc = fmaxf(acc, 0.f);
    float p = acc * W2[k];
    #pragma unroll
    for (int m = 32; m >= 1; m >>= 1) p += __shfl_xor(p, m);
    if (k == 0) out[idx] = p + b2[0];
}

// ---------------------------------------------------------------- launch
extern "C" void kernel_launch(void* const* d_in, const int* in_sizes, int n_in,
                              void* d_out, int out_size, void* d_ws, size_t ws_size,
                              hipStream_t stream) {
    const int* edge_src  = (const int*)d_in[0];
    const int* edge_dst  = (const int*)d_in[1];
    const int* edge_type = (const int*)d_in[2];
    const int* h_index   = (const int*)d_in[3];
    const int* t_index   = (const int*)d_in[4];
    const int* r_index   = (const int*)d_in[5];
    const float* rel_query = (const float*)d_in[7];
    const float* Wrel    = (const float*)d_in[8];
    const float* brel    = (const float*)d_in[9];
    const float* Wlin    = (const float*)d_in[10];
    const float* blin    = (const float*)d_in[11];
    const float* ln_g    = (const float*)d_in[12];
    const float* ln_b    = (const float*)d_in[13];
    const float* W1      = (const float*)d_in[14];
    const float* b1      = (const float*)d_in[15];
    const float* W2      = (const float*)d_in[16];
    const float* b2      = (const float*)d_in[17];

    const int N  = NNODE;
    const int E  = in_sizes[0];
    const int E2 = 2 * E;

    char* p = (char*)d_ws;
    auto carve = [&](size_t bytes) {
        void* r = (void*)p;
        p += (bytes + 255) & ~(size_t)255;
        return r;
    };
    float* x0      = (float*)carve((size_t)N * FEAT * 4);
    float* x1      = (float*)carve((size_t)N * FEAT * 4);
    int*   cnt     = (int*)carve((size_t)N * 4);
    int*   row_ptr = (int*)carve((size_t)(N + 1) * 4);
    int*   cursor  = (int*)carve((size_t)N * 4);
    int*   csr_src = (int*)carve((size_t)E2 * 4);
    int*   csr_et  = (int*)carve((size_t)E2 * 4);
    float* dinv    = (float*)carve((size_t)N * 4);
    float* logdeg  = (float*)carve((size_t)N * 4);
    float* scn     = (float*)carve((size_t)N * 4);
    float* meanp   = (float*)carve(16);
    float* rel_all = (float*)carve((size_t)NLAYER * NRELX2 * DDIM * 4);
    float* wg      = (float*)carve((size_t)NLAYER * 13 * 32 * 32 * 4);
    int*   h0      = (int*)carve(BS * 4);
    int*   r0      = (int*)carve(BS * 4);
    float* query   = (float*)carve(BS * DDIM * 4);
    int*   tnew    = (int*)carve(BS * NEG1 * 4);

    hipMemsetAsync(cnt, 0, (size_t)N * 4, stream);
    hipMemsetAsync(cursor, 0, (size_t)N * 4, stream);

    int eb = (E2 + 255) / 256;
    count_kernel<<<eb, 256, 0, stream>>>(edge_src, edge_dst, cnt, E);
    scan_kernel<<<1, 1024, 0, stream>>>(cnt, row_ptr, N);
    fill_kernel<<<eb, 256, 0, stream>>>(edge_src, edge_dst, edge_type, row_ptr,
                                        cursor, csr_src, csr_et, E);
    deg_kernel<<<(N + 255) / 256, 256, 0, stream>>>(cnt, dinv, logdeg, N);
    mean_kernel<<<1, 256, 0, stream>>>(logdeg, meanp, N);
    sc_kernel<<<(N + 255) / 256, 256, 0, stream>>>(logdeg, meanp, scn, N);
    prep_kernel<<<1, 256, 0, stream>>>(h_index, t_index, r_index, rel_query,
                                       h0, r0, query, tnew);
    rel_kernel<<<(NLAYER * NRELX2 * DDIM + 255) / 256, 256, 0, stream>>>(
        rel_query, Wrel, brel, rel_all);
    wg_kernel<<<(NLAYER * 13 * 32 * 32 + 255) / 256, 256, 0, stream>>>(Wlin, wg);
    init_x_kernel<<<(N * FEAT + 255) / 256, 256, 0, stream>>>(x0, h0, query);

    float* xin = x0;
    float* xout = x1;
    for (int i = 0; i < NLAYER; ++i) {
        layer_kernel<<<N / NPB, 256, 0, stream>>>(
            xin, xout, row_ptr, csr_src, csr_et,
            rel_all + (size_t)i * NRELX2 * DDIM,
            wg + (size_t)i * 13 * 32 * 32,
            blin + (size_t)i * DDIM,
            ln_g + (size_t)i * DDIM,
            ln_b + (size_t)i * DDIM,
            dinv, scn, h0, query);
        float* tmp = xin; xin = xout; xout = tmp;
    }

    score_kernel<<<BS * NEG1, 64, 0, stream>>>(xin, tnew, query, W1, b1, W2, b2,
                                               (float*)d_out);
}

// Round 3
// 838.565 us; speedup vs baseline: 3.5757x; 3.5757x over previous
//
#include <hip/hip_runtime.h>
#include <hip/hip_bf16.h>

// Problem constants fixed by setup_inputs()
#define NNODE   20000
#define BS      8
#define NEG1    33
#define DDIM    32
#define NLAYER  6
#define NRELX2  128     // 2*N_REL
#define FEAT    256     // BS*DDIM
#define INW     416     // 13*DDIM
#define NPB     16      // nodes per block
// NPG = 4 nodes per inner group, fully scalarized

// ---------------------------------------------------------------- precompute
__global__ void count_kernel(const int* __restrict__ es, const int* __restrict__ ed,
                             int* __restrict__ cnt, int E) {
    int i = blockIdx.x * 256 + threadIdx.x;
    if (i >= 2 * E) return;
    int dst = (i < E) ? ed[i] : es[i - E];
    atomicAdd(&cnt[dst], 1);
}

__global__ void scan_kernel(const int* __restrict__ cnt, int* __restrict__ row_ptr, int N) {
    __shared__ int sh[1024];
    __shared__ int s_carry;
    if (threadIdx.x == 0) { s_carry = 0; row_ptr[0] = 0; }
    __syncthreads();
    for (int base = 0; base < N; base += 1024) {
        int i = base + threadIdx.x;
        int v = (i < N) ? cnt[i] : 0;
        sh[threadIdx.x] = v;
        __syncthreads();
        for (int off = 1; off < 1024; off <<= 1) {
            int t = (threadIdx.x >= off) ? sh[threadIdx.x - off] : 0;
            __syncthreads();
            sh[threadIdx.x] += t;
            __syncthreads();
        }
        int carry = s_carry;
        if (i < N) row_ptr[i + 1] = carry + sh[threadIdx.x];
        __syncthreads();
        if (threadIdx.x == 1023) s_carry = carry + sh[1023];
        __syncthreads();
    }
}

__global__ void fill_kernel(const int* __restrict__ es, const int* __restrict__ ed,
                            const int* __restrict__ et, const int* __restrict__ row_ptr,
                            int* __restrict__ cursor, int* __restrict__ csr_src,
                            int* __restrict__ csr_et, int E) {
    int i = blockIdx.x * 256 + threadIdx.x;
    if (i >= 2 * E) return;
    int src, dst, ty;
    if (i < E) { src = es[i]; dst = ed[i]; ty = et[i]; }
    else       { src = ed[i - E]; dst = es[i - E]; ty = et[i - E] + 64; }
    int pos = row_ptr[dst] + atomicAdd(&cursor[dst], 1);
    csr_src[pos] = src;
    csr_et[pos]  = ty;
}

__global__ void deg_kernel(const int* __restrict__ cnt, float* __restrict__ dinv,
                           float* __restrict__ logdeg, int N) {
    int n = blockIdx.x * 256 + threadIdx.x;
    if (n >= N) return;
    float deg = (float)cnt[n] + 1.0f;
    dinv[n] = 1.0f / deg;
    logdeg[n] = logf(deg);
}

__global__ void mean_kernel(const float* __restrict__ logdeg, float* __restrict__ meanout, int N) {
    __shared__ float sh[256];
    float s = 0.f;
    for (int i = threadIdx.x; i < N; i += 256) s += logdeg[i];
    sh[threadIdx.x] = s;
    __syncthreads();
    for (int off = 128; off > 0; off >>= 1) {
        if (threadIdx.x < off) sh[threadIdx.x] += sh[threadIdx.x + off];
        __syncthreads();
    }
    if (threadIdx.x == 0) meanout[0] = sh[0] / (float)N;
}

__global__ void sc_kernel(const float* __restrict__ logdeg, const float* __restrict__ meanp,
                          float* __restrict__ sc, int N) {
    int n = blockIdx.x * 256 + threadIdx.x;
    if (n >= N) return;
    sc[n] = logdeg[n] / meanp[0];
}

__global__ void prep_kernel(const int* __restrict__ h_index, const int* __restrict__ t_index,
                            const int* __restrict__ r_index, const float* __restrict__ rel_query,
                            int* __restrict__ h0, int* __restrict__ r0,
                            float* __restrict__ query, int* __restrict__ tnew) {
    __shared__ int s_isneg[BS];
    __shared__ int s_r0[BS];
    int t = threadIdx.x;
    if (t < BS) {
        int b = t;
        int hv = h_index[b * NEG1];
        int all = 1;
        for (int j = 1; j < NEG1; j++) all &= (h_index[b * NEG1 + j] == hv);
        s_isneg[b] = all;
        int h0v = all ? hv : t_index[b * NEG1];
        int r0v = all ? r_index[b * NEG1] : r_index[b * NEG1] + 64;
        s_r0[b] = r0v;
        h0[b] = h0v;
        r0[b] = r0v;
    }
    __syncthreads();
    {
        int b = t >> 5, dd = t & 31;
        query[t] = rel_query[s_r0[b] * DDIM + dd];
    }
    for (int idx = t; idx < BS * NEG1; idx += 256) {
        int b = idx / NEG1;
        tnew[idx] = s_isneg[b] ? t_index[idx] : h_index[idx];
    }
}

__global__ void rel_kernel(const float* __restrict__ rel_query, const float* __restrict__ Wrel,
                           const float* __restrict__ brel, float* __restrict__ rel_all) {
    int idx = blockIdx.x * 256 + threadIdx.x;
    if (idx >= NLAYER * NRELX2 * DDIM) return;
    int i  = idx >> 12;          // / 4096
    int q  = (idx >> 5) & 127;
    int dd = idx & 31;
    float acc = brel[i * DDIM + dd];
    #pragma unroll
    for (int k = 0; k < DDIM; k++)
        acc = fmaf(rel_query[q * DDIM + k], Wrel[i * DDIM * DDIM + k * DDIM + dd], acc);
    rel_all[idx] = acc;
}

// Wg[i][j][c][dd] = Wlin[i][k_j(dd)][(dd+c)&31]  — systolic-shuffled weights
__global__ void wg_kernel(const float* __restrict__ Wlin, float* __restrict__ wg) {
    int idx = blockIdx.x * 256 + threadIdx.x;       // NLAYER*13*32*32
    if (idx >= NLAYER * 13 * 32 * 32) return;
    int dd = idx & 31;
    int c  = (idx >> 5) & 31;
    int rest = idx >> 10;       // i*13 + j
    int j = rest % 13;
    int i = rest / 13;
    int k;
    if (j == 0) k = dd;
    else { int s = (j - 1) / 3, scl = (j - 1) % 3; k = 32 + (dd * 4 + s) * 3 + scl; }
    int col = (dd + c) & 31;
    wg[idx] = Wlin[(i * INW + k) * DDIM + col];
}

__global__ void init_x_kernel(float* __restrict__ x, const int* __restrict__ h0,
                              const float* __restrict__ query) {
    int i = blockIdx.x * 256 + threadIdx.x;
    if (i >= NNODE * FEAT) return;
    int n = i >> 8;
    int t = i & 255;
    int b = t >> 5;
    x[i] = (h0[b] == n) ? query[t] : 0.f;
}

// ---------------------------------------------------------------- main layer
// Per block: NPB nodes, processed 4 at a time. All per-node state in named
// scalars (no arrays -> no scratch). GEMM via systolic accumulator rotation
// (1 ds_bpermute per acc per step) with pre-shuffled coalesced W.

#define STATS_COMP(U, NODE) {                                                 \
    int n_ = (NODE);                                                          \
    float bv_ = (h0b == n_) ? q : 0.f;                                        \
    float sum_ = bv_, ssq_ = bv_ * bv_, vmx_ = bv_, vmn_ = bv_;               \
    int e0_ = row_ptr[n_], e1_ = row_ptr[n_ + 1];                             \
    for (int e_ = e0_; e_ < e1_; ++e_) {                                      \
        int s_  = csr_src[e_];                                                \
        int ty_ = csr_et[e_];                                                 \
        float m_ = x_in[s_ * FEAT + t] * s_rel[ty_ * DDIM + dd];              \
        sum_ += m_; ssq_ += m_ * m_;                                          \
        vmx_ = fmaxf(vmx_, m_); vmn_ = fminf(vmn_, m_);                       \
    }                                                                         \
    float dv_ = dinv[n_];                                                     \
    mean##U = sum_ * dv_;                                                     \
    float sq_ = ssq_ * dv_;                                                   \
    mx##U = vmx_; mn##U = vmn_;                                               \
    sd##U = sqrtf(fmaxf(sq_ - mean##U * mean##U, 1e-6f));                     \
    float sv_ = sc[n_];                                                       \
    sv##U = sv_; s2##U = 1.0f / fmaxf(sv_, 0.01f);                            \
    xm##U = x_in[n_ * FEAT + t];                                              \
}

#define GSTEP(U) {                                                            \
    float a_ = acc##U;                                                        \
    a_ = fmaf(xm##U, w0, a_);                                                 \
    float t0_ = fmaf(sv##U, w2,  w1);  t0_ = fmaf(s2##U, w3,  t0_);           \
    a_ = fmaf(mean##U, t0_, a_);                                              \
    float t1_ = fmaf(sv##U, w5,  w4);  t1_ = fmaf(s2##U, w6,  t1_);           \
    a_ = fmaf(mx##U,   t1_, a_);                                              \
    float t2_ = fmaf(sv##U, w8,  w7);  t2_ = fmaf(s2##U, w9,  t2_);           \
    a_ = fmaf(mn##U,   t2_, a_);                                              \
    float t3_ = fmaf(sv##U, w11, w10); t3_ = fmaf(s2##U, w12, t3_);           \
    a_ = fmaf(sd##U,   t3_, a_);                                              \
    acc##U = a_;                                                              \
}

#define ROT(U) acc##U = __int_as_float(__builtin_amdgcn_ds_bpermute(          \
                            bperm_addr, __float_as_int(acc##U)));

#define LNSTORE(U, NODE) {                                                    \
    int n_ = (NODE);                                                          \
    float v_ = acc##U;                                                        \
    float s1_ = v_;                                                           \
    s1_ += __shfl_xor(s1_, 16, 32); s1_ += __shfl_xor(s1_, 8, 32);            \
    s1_ += __shfl_xor(s1_, 4, 32);  s1_ += __shfl_xor(s1_, 2, 32);            \
    s1_ += __shfl_xor(s1_, 1, 32);                                            \
    float lm_ = s1_ * (1.0f / 32.0f);                                         \
    float dl_ = v_ - lm_;                                                     \
    float p2_ = dl_ * dl_;                                                    \
    p2_ += __shfl_xor(p2_, 16, 32); p2_ += __shfl_xor(p2_, 8, 32);            \
    p2_ += __shfl_xor(p2_, 4, 32);  p2_ += __shfl_xor(p2_, 2, 32);            \
    p2_ += __shfl_xor(p2_, 1, 32);                                            \
    float var_ = p2_ * (1.0f / 32.0f);                                        \
    float y_ = dl_ / sqrtf(var_ + 1e-5f) * gdd + bdd;                         \
    y_ = fmaxf(y_, 0.0f);                                                     \
    x_out[n_ * FEAT + t] = y_ + xm##U;                                        \
}

__global__ __launch_bounds__(256, 2) void layer_kernel(
    const float* __restrict__ x_in, float* __restrict__ x_out,
    const int* __restrict__ row_ptr, const int* __restrict__ csr_src,
    const int* __restrict__ csr_et,
    const float* __restrict__ rel_i,     // [128][32]
    const float* __restrict__ wg_i,      // [13][32][32]
    const float* __restrict__ blin_i, const float* __restrict__ g_i,
    const float* __restrict__ b_i,
    const float* __restrict__ dinv, const float* __restrict__ sc,
    const int* __restrict__ h0, const float* __restrict__ query) {
    int t  = threadIdx.x;
    int b  = t >> 5, dd = t & 31;
    int lane = t & 63;
    __shared__ float s_rel[NRELX2 * DDIM];   // 16 KB

    for (int k = t; k < NRELX2 * DDIM; k += 256) s_rel[k] = rel_i[k];

    float q   = query[t];
    int   h0b = h0[b];
    float gdd = g_i[dd], bdd = b_i[dd], bl = blin_i[dd];
    // rotate-down-by-1 within each 32-lane half of the wave (pull from lane+1)
    int bperm_addr = ((((lane + 1) & 31) | (lane & 32)) << 2);
    __syncthreads();

    int nbase = blockIdx.x * NPB;
    #pragma unroll
    for (int g = 0; g < NPB; g += 4) {
        float xm0, mean0, mx0, mn0, sd0, sv0, s20;
        float xm1, mean1, mx1, mn1, sd1, sv1, s21;
        float xm2, mean2, mx2, mn2, sd2, sv2, s22;
        float xm3, mean3, mx3, mn3, sd3, sv3, s23;
        STATS_COMP(0, nbase + g + 0)
        STATS_COMP(1, nbase + g + 1)
        STATS_COMP(2, nbase + g + 2)
        STATS_COMP(3, nbase + g + 3)

        float acc0 = bl, acc1 = bl, acc2 = bl, acc3 = bl;
        #pragma unroll 8
        for (int i = 0; i < 32; ++i) {
            const float* wp = wg_i + i * 32 + dd;   // Wg[j][i][dd], j-stride 1024
            float w0  = wp[0 * 1024], w1  = wp[1 * 1024], w2  = wp[2 * 1024];
            float w3  = wp[3 * 1024], w4  = wp[4 * 1024], w5  = wp[5 * 1024];
            float w6  = wp[6 * 1024], w7  = wp[7 * 1024], w8  = wp[8 * 1024];
            float w9  = wp[9 * 1024], w10 = wp[10 * 1024], w11 = wp[11 * 1024];
            float w12 = wp[12 * 1024];
            GSTEP(0) GSTEP(1) GSTEP(2) GSTEP(3)
            ROT(0) ROT(1) ROT(2) ROT(3)
        }
        // 32 rotations = identity: lane dd again holds col dd

        LNSTORE(0, nbase + g + 0)
        LNSTORE(1, nbase + g + 1)
        LNSTORE(2, nbase + g + 2)
        LNSTORE(3, nbase + g + 3)
    }
}

// ---------------------------------------------------------------- readout
__global__ void score_kernel(const float* __restrict__ x, const int* __restrict__ tnew,
                             const float* __restrict__ query,
                             const float* __restrict__ W1, const float* __restrict__ b1,
                             const float* __restrict__ W2, const float* __restrict__ b2,
                             float* __restrict__ out) {
    int idx = blockIdx.x;         // b*33+j
    int b = idx / NEG1;
    int k = threadIdx.x;          // 0..63
    __shared__ float v[64];
    int tnode = tnew[idx];
    if (k < 32) v[k] = x[tnode * FEAT + b * DDIM + k];
    else        v[k] = query[b * DDIM + (k - 32)];
    __syncthreads();
    float acc = b1[k];
    #pragma unroll
    for (int l = 0; l < 64; l++) acc = fmaf(v[l], W1[l * 64 + k], acc);
    acc = fmaxf(acc, 0.f);
    float p = acc * W2[k];
    #pragma unroll
    for (int m = 32; m >= 1; m >>= 1) p += __shfl_xor(p, m);
    if (k == 0) out[idx] = p + b2[0];
}

// ---------------------------------------------------------------- launch
extern "C" void kernel_launch(void* const* d_in, const int* in_sizes, int n_in,
                              void* d_out, int out_size, void* d_ws, size_t ws_size,
                              hipStream_t stream) {
    const int* edge_src  = (const int*)d_in[0];
    const int* edge_dst  = (const int*)d_in[1];
    const int* edge_type = (const int*)d_in[2];
    const int* h_index   = (const int*)d_in[3];
    const int* t_index   = (const int*)d_in[4];
    const int* r_index   = (const int*)d_in[5];
    const float* rel_query = (const float*)d_in[7];
    const float* Wrel    = (const float*)d_in[8];
    const float* brel    = (const float*)d_in[9];
    const float* Wlin    = (const float*)d_in[10];
    const float* blin    = (const float*)d_in[11];
    const float* ln_g    = (const float*)d_in[12];
    const float* ln_b    = (const float*)d_in[13];
    const float* W1      = (const float*)d_in[14];
    const float* b1      = (const float*)d_in[15];
    const float* W2      = (const float*)d_in[16];
    const float* b2      = (const float*)d_in[17];

    const int N  = NNODE;
    const int E  = in_sizes[0];
    const int E2 = 2 * E;

    char* p = (char*)d_ws;
    auto carve = [&](size_t bytes) {
        void* r = (void*)p;
        p += (bytes + 255) & ~(size_t)255;
        return r;
    };
    float* x0      = (float*)carve((size_t)N * FEAT * 4);
    float* x1      = (float*)carve((size_t)N * FEAT * 4);
    int*   cnt     = (int*)carve((size_t)N * 4);
    int*   row_ptr = (int*)carve((size_t)(N + 1) * 4);
    int*   cursor  = (int*)carve((size_t)N * 4);
    int*   csr_src = (int*)carve((size_t)E2 * 4);
    int*   csr_et  = (int*)carve((size_t)E2 * 4);
    float* dinv    = (float*)carve((size_t)N * 4);
    float* logdeg  = (float*)carve((size_t)N * 4);
    float* scn     = (float*)carve((size_t)N * 4);
    float* meanp   = (float*)carve(16);
    float* rel_all = (float*)carve((size_t)NLAYER * NRELX2 * DDIM * 4);
    float* wg      = (float*)carve((size_t)NLAYER * 13 * 32 * 32 * 4);
    int*   h0      = (int*)carve(BS * 4);
    int*   r0      = (int*)carve(BS * 4);
    float* query   = (float*)carve(BS * DDIM * 4);
    int*   tnew    = (int*)carve(BS * NEG1 * 4);

    hipMemsetAsync(cnt, 0, (size_t)N * 4, stream);
    hipMemsetAsync(cursor, 0, (size_t)N * 4, stream);

    int eb = (E2 + 255) / 256;
    count_kernel<<<eb, 256, 0, stream>>>(edge_src, edge_dst, cnt, E);
    scan_kernel<<<1, 1024, 0, stream>>>(cnt, row_ptr, N);
    fill_kernel<<<eb, 256, 0, stream>>>(edge_src, edge_dst, edge_type, row_ptr,
                                        cursor, csr_src, csr_et, E);
    deg_kernel<<<(N + 255) / 256, 256, 0, stream>>>(cnt, dinv, logdeg, N);
    mean_kernel<<<1, 256, 0, stream>>>(logdeg, meanp, N);
    sc_kernel<<<(N + 255) / 256, 256, 0, stream>>>(logdeg, meanp, scn, N);
    prep_kernel<<<1, 256, 0, stream>>>(h_index, t_index, r_index, rel_query,
                                       h0, r0, query, tnew);
    rel_kernel<<<(NLAYER * NRELX2 * DDIM + 255) / 256, 256, 0, stream>>>(
        rel_query, Wrel, brel, rel_all);
    wg_kernel<<<(NLAYER * 13 * 32 * 32 + 255) / 256, 256, 0, stream>>>(Wlin, wg);
    init_x_kernel<<<(N * FEAT + 255) / 256, 256, 0, stream>>>(x0, h0, query);

    float* xin = x0;
    float* xout = x1;
    for (int i = 0; i < NLAYER; ++i) {
        layer_kernel<<<N / NPB, 256, 0, stream>>>(
            xin, xout, row_ptr, csr_src, csr_et,
            rel_all + (size_t)i * NRELX2 * DDIM,
            wg + (size_t)i * 13 * 32 * 32,
            blin + (size_t)i * DDIM,
            ln_g + (size_t)i * DDIM,
            ln_b + (size_t)i * DDIM,
            dinv, scn, h0, query);
        float* tmp = xin; xin = xout; xout = tmp;
    }

    score_kernel<<<BS * NEG1, 64, 0, stream>>>(xin, tnew, query, W1, b1, W2, b2,
                                               (float*)d_out);
}